// Round 4
// baseline (293.939 us; speedup 1.0000x reference)
//
#include <hip/hip_runtime.h>
#include <math.h>

// IDCT2 (DCT-III, ortho) over (16,32,256,256) fp32 via bf16 MFMA.
// Z = M * X * M^T, M[n][k] = w[k]*cos(pi*k*(2n+1)/512).
//
// Round-4 (= round-3 resubmit after infra failure; kernel audited clean).
// Single-barrier fused kernel. One block per half-batch (n-slice of 128).
//   Stage 1 (barrier-free): wave w owns i-rows [w*32, w*32+32) x all 128 n.
//     X fragments loaded DIRECTLY from global (2x float4 per frag) and
//     converted to bf16 in registers -- no LDS staging, no k-loop barriers.
//     M n-rows read from global; per-k-tile slice is 8 KB -> L1-resident.
//   Epilogue: W^T[n][i] bf16 -> LDS (XOR-swizzled), ONE __syncthreads().
//   Stage 2 (barrier-free): wave w owns m-rows [w*32,+32) x all 128 n.
//     A = W^T rows from LDS, B = M rows from L1/L2, direct fp32 stores.
// LDS = Wt only: 64 KB -> 2 blocks/CU, 16 independent waves/CU.

constexpr int N = 256;
typedef __attribute__((ext_vector_type(8))) short short8;
typedef __attribute__((ext_vector_type(4))) float f32x4;

__device__ __forceinline__ unsigned short f2bf(float f) {
    unsigned int u = __float_as_uint(f);
    u += 0x7fffu + ((u >> 16) & 1u);
    return (unsigned short)(u >> 16);
}

__device__ __forceinline__ short8 cvt8(float4 a, float4 b) {
    short8 r;
    r[0] = (short)f2bf(a.x); r[1] = (short)f2bf(a.y);
    r[2] = (short)f2bf(a.z); r[3] = (short)f2bf(a.w);
    r[4] = (short)f2bf(b.x); r[5] = (short)f2bf(b.y);
    r[6] = (short)f2bf(b.z); r[7] = (short)f2bf(b.w);
    return r;
}

__device__ __forceinline__ float mvalf(int n, int k) {
    const float CST = 0.006135923151542565f;  // pi/512
    const float W0  = 0.0625f;                // 1/sqrt(256)
    const float WK  = 0.08838834764831845f;   // sqrt(2/256)
    int q = (k * (2 * n + 1)) & 1023;
    return ((k == 0) ? W0 : WK) * __cosf(CST * (float)q);
}

__global__ __launch_bounds__(256) void mgen(unsigned short* __restrict__ Mg) {
    int idx = blockIdx.x * 256 + threadIdx.x;
    int n = idx >> 8, k = idx & 255;
    Mg[idx] = f2bf(mvalf(n, k));
}

__global__ __launch_bounds__(512, 4) void idct_fused3(
        const float* __restrict__ X,
        const unsigned short* __restrict__ Mg,
        float* __restrict__ Z) {
    // W^T tile: 128 rows (n) x 512 B (256 bf16 i-values), XOR-swizzled.
    __shared__ __align__(16) unsigned char Wt[65536];

    // Bijective XCD-chunked swizzle: the two halves of a batch land on bids
    // 8 apart -> same XCD under round-robin dispatch -> shared X in L2.
    const int bid = blockIdx.x, nb = gridDim.x;
    const int sw = ((nb & 7) == 0) ? ((bid & 7) * (nb >> 3) + (bid >> 3)) : bid;
    const int batch = sw >> 1;
    const int n0 = (sw & 1) << 7;               // n-slice base: 0 or 128

    const float* Xb = X + (size_t)batch * N * N;
    float*       Zb = Z + (size_t)batch * N * N;

    const int tid = threadIdx.x;
    const int w  = tid >> 6, l = tid & 63;
    const int q  = l >> 4, lr = l & 15;

    // ---------------- Stage 1: W^T (n-slice) -> LDS, barrier-free ----------
    // acc[r][c][j] = W[i = w*32 + r*16 + q*4 + j][n = n0 + c*16 + lr]
    f32x4 acc[2][8];
    #pragma unroll
    for (int r = 0; r < 2; ++r)
        #pragma unroll
        for (int c = 0; c < 8; ++c) acc[r][c] = f32x4{0.f, 0.f, 0.f, 0.f};

    const float* xr0 = Xb + (size_t)(w * 32 + lr) * N + q * 8;       // A rows (i)
    const unsigned short* mb = Mg + (size_t)(n0 + lr) * N + q * 8;   // B rows (n)

    // Depth-1 register prefetch of X fragments (HBM latency hides under MFMA).
    float4 xa00 = ((const float4*)(xr0 + 0 * N))[0];
    float4 xa01 = ((const float4*)(xr0 + 0 * N))[1];
    float4 xa10 = ((const float4*)(xr0 + 16 * N))[0];
    float4 xa11 = ((const float4*)(xr0 + 16 * N))[1];

    #pragma unroll 1
    for (int kt = 0; kt < 8; ++kt) {
        short8 afr[2];
        afr[0] = cvt8(xa00, xa01);
        afr[1] = cvt8(xa10, xa11);
        if (kt < 7) {
            const float* nx = xr0 + (kt + 1) * 32;
            xa00 = ((const float4*)(nx + 0 * N))[0];
            xa01 = ((const float4*)(nx + 0 * N))[1];
            xa10 = ((const float4*)(nx + 16 * N))[0];
            xa11 = ((const float4*)(nx + 16 * N))[1];
        }
        const unsigned short* mk = mb + kt * 32;
        __builtin_amdgcn_s_setprio(1);
        #pragma unroll
        for (int c = 0; c < 8; ++c) {
            short8 bf = *(const short8*)(mk + c * 16 * N);
            acc[0][c] = __builtin_amdgcn_mfma_f32_16x16x32_bf16(
                afr[0], bf, acc[0][c], 0, 0, 0);
            acc[1][c] = __builtin_amdgcn_mfma_f32_16x16x32_bf16(
                afr[1], bf, acc[1][c], 0, 0, 0);
        }
        __builtin_amdgcn_s_setprio(0);
    }

    // Epilogue: write W^T bf16 into LDS, swizzled (byte ^= (n&7)<<4).
    #pragma unroll
    for (int r = 0; r < 2; ++r)
        #pragma unroll
        for (int c = 0; c < 8; ++c) {
            ushort4 pw = {f2bf(acc[r][c][0]), f2bf(acc[r][c][1]),
                          f2bf(acc[r][c][2]), f2bf(acc[r][c][3])};
            int nloc = c * 16 + lr;
            int i2   = (w * 32 + r * 16 + q * 4) * 2;
            *(ushort4*)(Wt + nloc * 512 + (i2 ^ ((nloc & 7) << 4))) = pw;
        }
    __syncthreads();   // the kernel's ONLY barrier

    // ---------------- Stage 2: Z[:, n-slice] = M * W, barrier-free ---------
    // acc2[r][c][j] = Z[m = w*32 + c*16 + lr][n = n0 + r*16 + q*4 + j]
    f32x4 acc2[8][2];
    #pragma unroll
    for (int r = 0; r < 8; ++r)
        #pragma unroll
        for (int c = 0; c < 2; ++c) acc2[r][c] = f32x4{0.f, 0.f, 0.f, 0.f};

    const unsigned short* m2 = Mg + (size_t)(w * 32 + lr) * N + q * 8;  // B rows (m)

    #pragma unroll 2
    for (int it = 0; it < 8; ++it) {
        const int ib = it * 32 + q * 8;        // i-base for this lane
        short8 bf0 = *(const short8*)(m2 + it * 32);
        short8 bf1 = *(const short8*)(m2 + 16 * N + it * 32);
        __builtin_amdgcn_s_setprio(1);
        #pragma unroll
        for (int r = 0; r < 8; ++r) {
            int nloc = r * 16 + lr;
            short8 af = *(const short8*)(Wt + nloc * 512 +
                                         ((ib * 2) ^ ((nloc & 7) << 4)));
            acc2[r][0] = __builtin_amdgcn_mfma_f32_16x16x32_bf16(
                af, bf0, acc2[r][0], 0, 0, 0);
            acc2[r][1] = __builtin_amdgcn_mfma_f32_16x16x32_bf16(
                af, bf1, acc2[r][1], 0, 0, 0);
        }
        __builtin_amdgcn_s_setprio(0);
    }

    // Direct coalesced stores: lane owns 4 n-contiguous fp32 per (r,c).
    #pragma unroll
    for (int c = 0; c < 2; ++c) {
        const int m = w * 32 + c * 16 + lr;
        float* zr = Zb + (size_t)m * N + n0 + q * 4;
        #pragma unroll
        for (int r = 0; r < 8; ++r) {
            float4 v = make_float4(acc2[r][c][0], acc2[r][c][1],
                                   acc2[r][c][2], acc2[r][c][3]);
            *(float4*)(zr + r * 16) = v;
        }
    }
}

// ================= fp32 fallback (ws too small) — round-1 kernels =========
__global__ __launch_bounds__(256) void idct_cols(const float* __restrict__ X,
                                                 float* __restrict__ Y) {
    const int n0 = blockIdx.x * 64;
    const int i0 = blockIdx.y * 64;
    const float* Xb = X + (size_t)blockIdx.z * N * N;
    float* Yb = Y + (size_t)blockIdx.z * N * N;
    __shared__ float Ast[16][68];
    __shared__ float Bs[16][68];
    const int tid = threadIdx.x;
    const int tx = tid & 15, ty = tid >> 4;
    float acc[4][4] = {};
    for (int k0 = 0; k0 < N; k0 += 16) {
        {
            int r = tid >> 2, c4 = (tid & 3) << 2;
            float4 v = *reinterpret_cast<const float4*>(Xb + (size_t)(i0 + r) * N + k0 + c4);
            Ast[c4 + 0][r] = v.x; Ast[c4 + 1][r] = v.y;
            Ast[c4 + 2][r] = v.z; Ast[c4 + 3][r] = v.w;
        }
        #pragma unroll
        for (int j = 0; j < 4; ++j) {
            int ll = tid + 256 * j;
            Bs[ll >> 6][ll & 63] = mvalf(n0 + (ll & 63), k0 + (ll >> 6));
        }
        __syncthreads();
        #pragma unroll
        for (int kk = 0; kk < 16; ++kk) {
            float4 av = *reinterpret_cast<const float4*>(&Ast[kk][ty << 2]);
            float4 bv = *reinterpret_cast<const float4*>(&Bs[kk][tx << 2]);
            float a[4] = {av.x, av.y, av.z, av.w};
            float bb[4] = {bv.x, bv.y, bv.z, bv.w};
            #pragma unroll
            for (int r = 0; r < 4; ++r)
                #pragma unroll
                for (int c = 0; c < 4; ++c) acc[r][c] += a[r] * bb[c];
        }
        __syncthreads();
    }
    #pragma unroll
    for (int r = 0; r < 4; ++r) {
        float4 v = make_float4(acc[r][0], acc[r][1], acc[r][2], acc[r][3]);
        *reinterpret_cast<float4*>(Yb + (size_t)(i0 + (ty << 2) + r) * N + n0 + (tx << 2)) = v;
    }
}

__global__ __launch_bounds__(512) void idct_rows_inplace(float* __restrict__ Y) {
    const int n0 = blockIdx.x * 64;
    float* Yb = Y + (size_t)blockIdx.y * N * N;
    __shared__ float Ys[256][68];
    __shared__ float Ms[16][256];
    const int tid = threadIdx.x;
    #pragma unroll
    for (int j = 0; j < 8; ++j) {
        int ll = tid + 512 * j;
        int row = ll >> 4, c4 = (ll & 15) << 2;
        *reinterpret_cast<float4*>(&Ys[row][c4]) =
            *reinterpret_cast<const float4*>(Yb + (size_t)row * N + n0 + c4);
    }
    __syncthreads();
    const int tx = tid & 15, ty = tid >> 4;
    float acc[8][4] = {};
    for (int i0 = 0; i0 < N; i0 += 16) {
        __syncthreads();
        #pragma unroll
        for (int j = 0; j < 8; ++j) {
            int ll = tid + 512 * j;
            Ms[ll >> 8][ll & 255] = mvalf(ll & 255, i0 + (ll >> 8));
        }
        __syncthreads();
        #pragma unroll
        for (int ii = 0; ii < 16; ++ii) {
            float bb[4];
            #pragma unroll
            for (int c = 0; c < 4; ++c) bb[c] = Ys[i0 + ii][(tx << 2) + c];
            #pragma unroll
            for (int r = 0; r < 8; ++r) {
                float a = Ms[ii][(ty << 3) + r];
                #pragma unroll
                for (int c = 0; c < 4; ++c) acc[r][c] += a * bb[c];
            }
        }
    }
    #pragma unroll
    for (int r = 0; r < 8; ++r) {
        float4 v = make_float4(acc[r][0], acc[r][1], acc[r][2], acc[r][3]);
        *reinterpret_cast<float4*>(Yb + (size_t)((ty << 3) + r) * N + n0 + (tx << 2)) = v;
    }
}

extern "C" void kernel_launch(void* const* d_in, const int* in_sizes, int n_in,
                              void* d_out, int out_size, void* d_ws, size_t ws_size,
                              hipStream_t stream) {
    const float* X = (const float*)d_in[0];
    float* out = (float*)d_out;
    const int total = in_sizes[0];
    const int Bn = total / (N * N);   // 512
    const size_t needM = (size_t)N * N * 2;   // M bf16 in workspace

    if (ws_size >= needM) {
        unsigned short* Mg = (unsigned short*)d_ws;
        mgen<<<N * N / 256, 256, 0, stream>>>(Mg);
        idct_fused3<<<dim3(Bn * 2), 512, 0, stream>>>(X, Mg, out);
    } else {
        idct_cols<<<dim3(N / 64, N / 64, Bn), 256, 0, stream>>>(X, out);
        idct_rows_inplace<<<dim3(N / 64, Bn), 512, 0, stream>>>(out);
    }
}